// Round 1
// baseline (528.444 us; speedup 1.0000x reference)
//
#include <hip/hip_runtime.h>
#include <math.h>

// Problem constants (shapes fixed by setup_inputs)
namespace {
constexpr int B_ = 2;
constexpr int L_ = 1024;
constexpr int K_ = 50;        // topk = min(L, params=50)
constexpr int HID_ = 768;
constexpr int PE_ = 384;
constexpr int HALF_ = 192;
constexpr int TROWS_ = 1024;  // INIT (sinusoidal table rows)

typedef float f32x4 __attribute__((ext_vector_type(4)));

// d_out layout (float elements, outputs concatenated in return order)
constexpr long long OUT0 = 0;                                     // layout_emb [B,L,HID]
constexpr long long OUT1 = OUT0 + (long long)B_ * L_ * HID_;      // p [B,L,K,HID]
constexpr long long OUT2 = OUT1 + (long long)B_ * L_ * K_ * HID_; // topk_index [B,L,K]
constexpr long long OUT3 = OUT2 + (long long)B_ * L_ * K_;        // local_mask [B,L,L]

// workspace layout (float elements)
constexpr long long WS_SIN = 0;                                   // sin_tab [1024,384]
constexpr long long WS_T   = WS_SIN + (long long)TROWS_ * PE_;    // T tables 4x[1024,768]
constexpr long long WS_TI  = WS_T + 4LL * TROWS_ * HID_;          // topk indices (int) [B*L*K]

// mega-kernel block roles
constexpr int GEMM_BLOCKS = 16 * 12 * 4;   // 768 tiles: 16 r-tiles x 12 o-tiles x 4 tables
constexpr int TOPK_BLOCKS = B_ * L_;       // 2048
constexpr int LN_BLOCKS   = B_ * L_;       // 2048
}

// ---------------------------------------------------------------------------
// Sinusoidal table: tab[r, j] = sin(r*freq_j), tab[r, 192+j] = cos(r*freq_j),
// row 0 zeroed (padding_idx). freq_j = exp(j * -ln(10000)/191), fp32 like numpy.
// ---------------------------------------------------------------------------
__global__ __launch_bounds__(192) void k_sin_tab(float* __restrict__ tab) {
    const int r = blockIdx.x;
    const int j = threadIdx.x;
    const float c = -0.04822168780092243f;  // -ln(10000)/191
    float fr = expf((float)j * c);
    float ang = (float)r * fr;
    float s, co;
    if (r == 0) { s = 0.f; co = 0.f; } else { s = sinf(ang); co = cosf(ang); }
    tab[r * PE_ + j] = s;
    tab[r * PE_ + HALF_ + j] = co;
}

// ---------------------------------------------------------------------------
// Shared-memory union for the fused mega kernel (roles never mix in a block).
// GEMM role needs the most: 2 x 32 x 68 floats = 17408 B.
// ---------------------------------------------------------------------------
union SMem {
    struct { float As[32][68]; float Bs[32][68]; } g;                  // GEMM staging
    struct { float xs[L_]; float ys[L_]; float mrow[L_];
             unsigned long long wmin[4]; } t;                          // topk
    struct { float red[4]; } l;                                       // layernorm
};

__device__ __forceinline__ float block_sum_256(float x, float* red) {
    #pragma unroll
    for (int off = 32; off > 0; off >>= 1) x += __shfl_xor(x, off, 64);
    const int wave = threadIdx.x >> 6;
    if ((threadIdx.x & 63) == 0) red[wave] = x;
    __syncthreads();
    float t = red[0] + red[1] + red[2] + red[3];
    __syncthreads();
    return t;
}

// ---------------------------------------------------------------------------
// Mega kernel: three independent roles fused into one launch so the VALU-bound
// GEMM tiles overlap the barrier-latency topk blocks and the memory-ish LN
// blocks instead of running serialized.
//
// Role 0 (blocks [0,768)): combined tables
//   T_t[r,o] = sum_j U_t[o,j] * sin_tab[r,j]
//     t=0: U = W_tl[:, :384] + W_bl[:, :384]   (ex1; biases folded in)
//     t=1: U = W_tr[:, :384] + W_br[:, :384]   (ex2)
//     t=2: U = W_tl[:, 384:] + W_tr[:, 384:]   (ey1)
//     t=3: U = W_bl[:, 384:] + W_br[:, 384:]   (ey2)
//   BM=64 x BN=64 x BK=32, 256 thr, 4x4/thread. LDS rows padded to 68 floats
//   (272 B, 16B-aligned) so fragments are ds_read_b128; float4 staging loads.
//   FMA order identical to the previous 5-kernel version (bitwise-same T).
//
// Role 1 (blocks [768,2816)): exact top-50 argmin rounds + mask row.
// Role 2 (blocks [2816,4864)): layout_emb gather + LayerNorm(768).
// ---------------------------------------------------------------------------
__global__ __launch_bounds__(256) void k_mega(
    const float* __restrict__ sinT,
    const float* __restrict__ Wtl, const float* __restrict__ Wtr,
    const float* __restrict__ Wbl, const float* __restrict__ Wbr,
    const float* __restrict__ btl, const float* __restrict__ btr,
    const float* __restrict__ bbl, const float* __restrict__ bbr,
    float* __restrict__ Tout,
    const int4* __restrict__ bbox, const int* __restrict__ am,
    float* __restrict__ topk_f, int* __restrict__ topk_i, float* __restrict__ mask,
    const float* __restrict__ xt, const float* __restrict__ yt,
    const float* __restrict__ ht, const float* __restrict__ wt,
    const float* __restrict__ lng, const float* __restrict__ lnb,
    float* __restrict__ lout)
{
    __shared__ SMem sm;
    const int bid = blockIdx.x;
    const int tid = threadIdx.x;

    if (bid < GEMM_BLOCKS) {
        // ---------------- Role 0: build T ----------------
        const int t   = bid / 192;
        const int rem = bid - t * 192;
        const int rx  = rem & 15;
        const int oy  = rem >> 4;
        const float* Wa; const float* Wb; int coff;
        if (t == 0)      { Wa = Wtl; Wb = Wbl; coff = 0; }
        else if (t == 1) { Wa = Wtr; Wb = Wbr; coff = 0; }
        else if (t == 2) { Wa = Wtl; Wb = Wtr; coff = PE_; }
        else             { Wa = Wbl; Wb = Wbr; coff = PE_; }

        const int r0 = rx * 64;
        const int o0 = oy * 64;
        const int ty = tid >> 4, tx = tid & 15;
        float acc[4][4] = {{0.f,0.f,0.f,0.f},{0.f,0.f,0.f,0.f},
                           {0.f,0.f,0.f,0.f},{0.f,0.f,0.f,0.f}};

        for (int k0 = 0; k0 < PE_; k0 += 32) {
            // stage A (64r x 32k) and B=Wa+Wb (64o x 32k) as float4
            #pragma unroll
            for (int s = 0; s < 2; ++s) {
                int idx = s * 256 + tid;          // 0..511
                int rr = idx >> 3, q = idx & 7;   // row 0..63, 16B-chunk 0..7
                f32x4 av = *(const f32x4*)&sinT[(r0 + rr) * PE_ + k0 + q * 4];
                f32x4 w1 = *(const f32x4*)&Wa[(o0 + rr) * (2 * PE_) + coff + k0 + q * 4];
                f32x4 w2 = *(const f32x4*)&Wb[(o0 + rr) * (2 * PE_) + coff + k0 + q * 4];
                f32x4 bv = w1 + w2;
                #pragma unroll
                for (int c = 0; c < 4; ++c) {
                    sm.g.As[q * 4 + c][rr] = av[c];
                    sm.g.Bs[q * 4 + c][rr] = bv[c];
                }
            }
            __syncthreads();
            #pragma unroll
            for (int kk = 0; kk < 32; ++kk) {
                f32x4 a = *(const f32x4*)&sm.g.As[kk][ty * 4];  // 272B row stride: aligned
                f32x4 b = *(const f32x4*)&sm.g.Bs[kk][tx * 4];
                #pragma unroll
                for (int m = 0; m < 4; ++m)
                    #pragma unroll
                    for (int n = 0; n < 4; ++n)
                        acc[m][n] = fmaf(a[m], b[n], acc[m][n]);
            }
            __syncthreads();
        }

        #pragma unroll
        for (int m = 0; m < 4; ++m) {
            int r = r0 + ty * 4 + m;
            f32x4 v;
            #pragma unroll
            for (int n = 0; n < 4; ++n) {
                int o = o0 + tx * 4 + n;
                float x = acc[m][n];
                if (t == 0) x += btl[o] + btr[o] + bbl[o] + bbr[o];  // bias fold
                v[n] = x;
            }
            *(f32x4*)&Tout[(long long)t * TROWS_ * HID_ + (long long)r * HID_ + o0 + tx * 4] = v;
        }
        return;
    }

    if (bid < GEMM_BLOCKS + TOPK_BLOCKS) {
        // ---------------- Role 1: top-k + local mask ----------------
        const int bi = bid - GEMM_BLOCKS;
        const int b = bi >> 10;
        const int i = bi & 1023;
        for (int j = tid; j < L_; j += 256) {
            int4 q = bbox[b * L_ + j];
            float x1, y1, x2, y2;
            if (am[b * L_ + j] == 0) { x1 = y1 = x2 = y2 = 1e8f; }
            else { x1 = (float)q.x; y1 = (float)q.y; x2 = (float)q.z; y2 = (float)q.w; }
            sm.t.xs[j] = (x1 + x2) * 0.5f;
            sm.t.ys[j] = (y1 + y2) * 0.5f;
            sm.t.mrow[j] = 0.f;
        }
        __syncthreads();
        const float xq = sm.t.xs[i], yq = sm.t.ys[i];
        unsigned long long key[4];
        #pragma unroll
        for (int s = 0; s < 4; ++s) {
            int j = tid + s * 256;
            float dx = xq - sm.t.xs[j], dy = yq - sm.t.ys[j];
            float d = dx * dx + dy * dy;   // exact in fp32 (multiples of 0.25)
            key[s] = ((unsigned long long)__float_as_uint(d) << 32) | (unsigned int)j;
        }
        const int lane = tid & 63, wave = tid >> 6;
        const long long obase = (long long)(b * L_ + i) * K_;
        for (int r = 0; r < K_; ++r) {
            unsigned long long m = key[0] < key[1] ? key[0] : key[1];
            unsigned long long m2 = key[2] < key[3] ? key[2] : key[3];
            if (m2 < m) m = m2;
            #pragma unroll
            for (int off = 1; off < 64; off <<= 1) {
                unsigned long long o = __shfl_xor(m, off, 64);
                if (o < m) m = o;
            }
            if (lane == 0) sm.t.wmin[wave] = m;
            __syncthreads();
            unsigned long long mm = sm.t.wmin[0] < sm.t.wmin[1] ? sm.t.wmin[0] : sm.t.wmin[1];
            unsigned long long mb = sm.t.wmin[2] < sm.t.wmin[3] ? sm.t.wmin[2] : sm.t.wmin[3];
            if (mb < mm) mm = mb;
            if (tid == 0) {
                int w = (int)(mm & 0xffffffffu);
                topk_f[obase + r] = (float)w;
                topk_i[obase + r] = w;
                sm.t.mrow[w] = 1.0f;
            }
            #pragma unroll
            for (int s = 0; s < 4; ++s) if (key[s] == mm) key[s] = ~0ULL;  // remove winner
            __syncthreads();
        }
        f32x4* mrow = (f32x4*)(mask + (long long)(b * L_ + i) * L_);
        const f32x4* src = (const f32x4*)sm.t.mrow;
        __builtin_nontemporal_store(src[tid], mrow + tid);
        return;
    }

    // ---------------- Role 2: layout_emb + LayerNorm ----------------
    {
        const int tok = bid - (GEMM_BLOCKS + TOPK_BLOCKS);
        const int4 q = bbox[tok];
        float v[3];
        #pragma unroll
        for (int s = 0; s < 3; ++s) {
            int e = tid + s * 256;
            int off = e & 127;
            int seg = e >> 7;
            float val;
            if (seg == 0)      val = xt[q.x * 128 + off];
            else if (seg == 1) val = yt[q.y * 128 + off];
            else if (seg == 2) val = xt[q.z * 128 + off];
            else if (seg == 3) val = yt[q.w * 128 + off];
            else if (seg == 4) val = ht[(q.w - q.y) * 128 + off];
            else               val = wt[(q.z - q.x) * 128 + off];
            v[s] = val;
        }
        float mu = block_sum_256(v[0] + v[1] + v[2], sm.l.red) * (1.0f / 768.0f);
        float sq = 0.f;
        #pragma unroll
        for (int s = 0; s < 3; ++s) { float d = v[s] - mu; sq = fmaf(d, d, sq); }
        float var = block_sum_256(sq, sm.l.red) * (1.0f / 768.0f);
        float inv = 1.0f / sqrtf(var + 1e-12f);
        float* orow = lout + (long long)tok * HID_;
        #pragma unroll
        for (int s = 0; s < 3; ++s) {
            int e = tid + s * 256;
            __builtin_nontemporal_store((v[s] - mu) * inv * lng[e] + lnb[e], orow + e);
        }
    }
}

// ---------------------------------------------------------------------------
// p assembly: p[row,:] = T1[r1] + T2[r2] + T3[r3] + T4[r4]  (bias in T1)
// One wave per row, float4 loads. Non-temporal stores keep the 315 MB write
// stream out of L2 so the hot T rows (KNN deltas cluster near 0) stay cached.
// ---------------------------------------------------------------------------
__device__ __forceinline__ int wrapc(int d) {
    d = d < -1000 ? -1000 : (d > 1000 ? 1000 : d);  // clip [1-MAX2D, MAX2D-1]
    return (d + 1024) & 1023;                        // mod INIT (d >= -1000)
}

__global__ __launch_bounds__(256) void k_passemble(
    const int4* __restrict__ bbox, const int* __restrict__ topk_i,
    const f32x4* __restrict__ T, float* __restrict__ p)
{
    const int row = blockIdx.x * 4 + (threadIdx.x >> 6);  // (b*L+i)*K + k
    const int lane = threadIdx.x & 63;
    const int b = row / (L_ * K_);
    const int rem = row - b * (L_ * K_);
    const int i = rem / K_;
    const int j = topk_i[row];
    const int4 bi = bbox[b * L_ + i];
    const int4 bj = bbox[b * L_ + j];
    const f32x4* T1 = T + (long long)wrapc(bi.x - bj.x) * 192;              // ex1
    const f32x4* T2 = T + 196608 + (long long)wrapc(bi.z - bj.z) * 192;     // ex2
    const f32x4* T3 = T + 2 * 196608 + (long long)wrapc(bi.y - bj.y) * 192; // ey1
    const f32x4* T4 = T + 3 * 196608 + (long long)wrapc(bi.w - bj.w) * 192; // ey2
    f32x4* prow = (f32x4*)p + (long long)row * 192;
    #pragma unroll
    for (int u = 0; u < 3; ++u) {
        int f = lane + u * 64;
        f32x4 o = T1[f] + T2[f] + T3[f] + T4[f];
        __builtin_nontemporal_store(o, prow + f);
    }
}

// ---------------------------------------------------------------------------
extern "C" void kernel_launch(void* const* d_in, const int* in_sizes, int n_in,
                              void* d_out, int out_size, void* d_ws, size_t ws_size,
                              hipStream_t stream)
{
    const int4* bbox = (const int4*)d_in[0];
    const int* am    = (const int*)d_in[1];
    const float* xt  = (const float*)d_in[2];
    const float* yt  = (const float*)d_in[3];
    const float* ht  = (const float*)d_in[4];
    const float* wt  = (const float*)d_in[5];
    const float* Wtl = (const float*)d_in[6];
    const float* btl = (const float*)d_in[7];
    const float* Wtr = (const float*)d_in[8];
    const float* btr = (const float*)d_in[9];
    const float* Wbl = (const float*)d_in[10];
    const float* bbl = (const float*)d_in[11];
    const float* Wbr = (const float*)d_in[12];
    const float* bbr = (const float*)d_in[13];
    const float* lng = (const float*)d_in[14];
    const float* lnb = (const float*)d_in[15];
    // d_in[16] = params (50) — baked into K_

    float* out = (float*)d_out;
    float* ws = (float*)d_ws;
    float* sinT = ws + WS_SIN;
    float* T = ws + WS_T;
    int* topk_i = (int*)(ws + WS_TI);

    k_sin_tab<<<dim3(TROWS_), dim3(HALF_), 0, stream>>>(sinT);
    k_mega<<<dim3(GEMM_BLOCKS + TOPK_BLOCKS + LN_BLOCKS), dim3(256), 0, stream>>>(
        sinT, Wtl, Wtr, Wbl, Wbr, btl, btr, bbl, bbr, T,
        bbox, am, out + OUT2, topk_i, out + OUT3,
        xt, yt, ht, wt, lng, lnb, out + OUT0);
    k_passemble<<<dim3(B_ * L_ * K_ / 4), dim3(256), 0, stream>>>(
        bbox, topk_i, (const f32x4*)T, out + OUT1);
}

// Round 2
// 525.499 us; speedup vs baseline: 1.0056x; 1.0056x over previous
//
#include <hip/hip_runtime.h>
#include <math.h>

// Problem constants (shapes fixed by setup_inputs)
namespace {
constexpr int B_ = 2;
constexpr int L_ = 1024;
constexpr int K_ = 50;        // topk = min(L, params=50)
constexpr int HID_ = 768;
constexpr int PE_ = 384;
constexpr int HALF_ = 192;
constexpr int TROWS_ = 1024;  // INIT (sinusoidal table rows)

typedef float f32x4 __attribute__((ext_vector_type(4)));
typedef _Float16 f16x4 __attribute__((ext_vector_type(4)));
typedef _Float16 f16x8 __attribute__((ext_vector_type(8)));

// d_out layout (float elements, outputs concatenated in return order)
constexpr long long OUT0 = 0;                                     // layout_emb [B,L,HID]
constexpr long long OUT1 = OUT0 + (long long)B_ * L_ * HID_;      // p [B,L,K,HID]
constexpr long long OUT2 = OUT1 + (long long)B_ * L_ * K_ * HID_; // topk_index [B,L,K]
constexpr long long OUT3 = OUT2 + (long long)B_ * L_ * K_;        // local_mask [B,L,L]

// workspace layout (float elements)
constexpr long long WS_ST = 0;                                    // sin^T [384][1024] f32
constexpr long long WS_UT = WS_ST + (long long)PE_ * TROWS_;      // U^T [4][384][768] f32
constexpr long long WS_T  = WS_UT + 4LL * PE_ * HID_;             // T fp16 [4][1024][768] (= 2x f32 elems)
constexpr long long WS_TI = WS_T + 2LL * TROWS_ * HID_;           // topk indices (int) [B*L*K]

// mega-kernel block roles
constexpr int GEMM_BLOCKS = 8 * 6 * 4;     // 192 tiles: 8 r-tiles x 6 o-tiles x 4 tables (128x128)
constexpr int TOPK_BLOCKS = B_ * L_;       // 2048
constexpr int LN_BLOCKS   = B_ * L_;       // 2048
}

// ---------------------------------------------------------------------------
// Pre-kernel, two roles:
//  role A (blocks [0,384)): sin^T[k][r]: k<192 -> sin(r*f_k), k>=192 -> cos(r*f_{k-192});
//    column r=0 zeroed (padding_idx). Same expf/sinf/cosf formulas as before.
//  role B (blocks [384,672)): U^T[t][j][o] = Wa[o][coff+j] + Wb[o][coff+j]
//    (the 4 combined weight matrices, transposed k-major for the no-LDS GEMM).
// ---------------------------------------------------------------------------
__global__ __launch_bounds__(256) void k_pre(
    const float* __restrict__ Wtl, const float* __restrict__ Wtr,
    const float* __restrict__ Wbl, const float* __restrict__ Wbr,
    float* __restrict__ ST, float* __restrict__ UT)
{
    __shared__ float tile[64][68];
    const int bid = blockIdx.x;
    const int tid = threadIdx.x;

    if (bid < PE_) {
        const int jj = bid < HALF_ ? bid : bid - HALF_;
        const float c = -0.04822168780092243f;  // -ln(10000)/191
        float fr = expf((float)jj * c);
        #pragma unroll
        for (int s = 0; s < 4; ++s) {
            int r = tid + s * 256;
            float ang = (float)r * fr;
            float v;
            if (r == 0) v = 0.f;
            else        v = (bid < HALF_) ? sinf(ang) : cosf(ang);
            ST[bid * TROWS_ + r] = v;
        }
        return;
    }

    int rem = bid - PE_;
    const int t = rem / 72; rem -= t * 72;          // 12 o-tiles x 6 j-tiles
    const int o0 = (rem % 12) * 64;
    const int j0 = (rem / 12) * 64;
    const float* Wa; const float* Wb; int coff;
    if (t == 0)      { Wa = Wtl; Wb = Wbl; coff = 0; }
    else if (t == 1) { Wa = Wtr; Wb = Wbr; coff = 0; }
    else if (t == 2) { Wa = Wtl; Wb = Wtr; coff = PE_; }
    else             { Wa = Wbl; Wb = Wbr; coff = PE_; }

    #pragma unroll
    for (int p = 0; p < 4; ++p) {
        int oo = (tid >> 4) + p * 16;
        int jq = tid & 15;
        f32x4 w1 = *(const f32x4*)&Wa[(long long)(o0 + oo) * (2 * PE_) + coff + j0 + jq * 4];
        f32x4 w2 = *(const f32x4*)&Wb[(long long)(o0 + oo) * (2 * PE_) + coff + j0 + jq * 4];
        f32x4 s = w1 + w2;
        #pragma unroll
        for (int c = 0; c < 4; ++c) tile[jq * 4 + c][oo] = s[c];
    }
    __syncthreads();
    #pragma unroll
    for (int p = 0; p < 4; ++p) {
        int jj = (tid >> 4) + p * 16;
        int oq = tid & 15;
        f32x4 v = *(const f32x4*)&tile[jj][oq * 4];
        *(f32x4*)&UT[((long long)t * PE_ + j0 + jj) * HID_ + o0 + oq * 4] = v;
    }
}

// ---------------------------------------------------------------------------
// Shared-memory union for the fused mega kernel (GEMM role now uses NO LDS).
// ---------------------------------------------------------------------------
union SMemM {
    struct { float xs[L_]; float ys[L_]; float mrow[L_];
             unsigned long long wmin[4]; } t;                      // topk (12320 B)
    struct { float red[4]; } l;                                    // layernorm
};

__device__ __forceinline__ float block_sum_256(float x, float* red) {
    #pragma unroll
    for (int off = 32; off > 0; off >>= 1) x += __shfl_xor(x, off, 64);
    const int wave = threadIdx.x >> 6;
    if ((threadIdx.x & 63) == 0) red[wave] = x;
    __syncthreads();
    float t = red[0] + red[1] + red[2] + red[3];
    __syncthreads();
    return t;
}

// ---------------------------------------------------------------------------
// Mega kernel.
// Role 0 (blocks [0,192)): T_t[r,o] = sum_j U^T[t][j][o] * sin^T[j][r]
//   128x128 tile, 8x8 per thread, operands read straight from L2-resident
//   global (per-block unique traffic ~400 KB) -> no LDS, no barriers, no
//   bank conflicts. k ascending per output: identical fp32 summation order
//   to the previous version; result stored fp16 (only the final rounding
//   changes, <= 2^-11 relative).
// Role 1 (blocks [192,2240)): exact top-50 + local mask (unchanged).
// Role 2 (blocks [2240,4288)): layout_emb gather + LayerNorm (unchanged).
// __launch_bounds__(256,4): cap VGPR <=128 so topk keeps 16 waves/CU.
// ---------------------------------------------------------------------------
__global__ __launch_bounds__(256, 4) void k_mega(
    const float* __restrict__ ST, const float* __restrict__ UT,
    const float* __restrict__ btl, const float* __restrict__ btr,
    const float* __restrict__ bbl, const float* __restrict__ bbr,
    _Float16* __restrict__ Th,
    const int4* __restrict__ bbox, const int* __restrict__ am,
    float* __restrict__ topk_f, int* __restrict__ topk_i, float* __restrict__ mask,
    const float* __restrict__ xt, const float* __restrict__ yt,
    const float* __restrict__ ht, const float* __restrict__ wt,
    const float* __restrict__ lng, const float* __restrict__ lnb,
    float* __restrict__ lout)
{
    __shared__ SMemM sm;
    const int bid = blockIdx.x;
    const int tid = threadIdx.x;

    if (bid < GEMM_BLOCKS) {
        // ---------------- Role 0: build T (no-LDS GEMM) ----------------
        const int t   = bid / 48;
        const int rem = bid - t * 48;
        const int r0  = (rem & 7) * 128;
        const int o0  = (rem >> 3) * 128;
        const int ty = tid >> 4, tx = tid & 15;

        const float* A  = ST + r0 + ty * 8;                         // [k][r] k-major
        const float* Bp = UT + (long long)t * PE_ * HID_ + o0 + tx * 8;  // [k][o]

        float acc[8][8];
        #pragma unroll
        for (int m = 0; m < 8; ++m)
            #pragma unroll
            for (int n = 0; n < 8; ++n) acc[m][n] = 0.f;

        #pragma unroll 2
        for (int kk = 0; kk < PE_; ++kk) {
            f32x4 a0 = *(const f32x4*)&A[(long long)kk * TROWS_];
            f32x4 a1 = *(const f32x4*)&A[(long long)kk * TROWS_ + 4];
            f32x4 b0 = *(const f32x4*)&Bp[(long long)kk * HID_];
            f32x4 b1 = *(const f32x4*)&Bp[(long long)kk * HID_ + 4];
            #pragma unroll
            for (int m = 0; m < 8; ++m) {
                float av = (m < 4) ? a0[m] : a1[m - 4];
                #pragma unroll
                for (int n = 0; n < 4; ++n) {
                    acc[m][n]     = fmaf(av, b0[n], acc[m][n]);
                    acc[m][n + 4] = fmaf(av, b1[n], acc[m][n + 4]);
                }
            }
        }

        #pragma unroll
        for (int m = 0; m < 8; ++m) {
            int r = r0 + ty * 8 + m;
            f16x8 h;
            #pragma unroll
            for (int n = 0; n < 8; ++n) {
                int o = o0 + tx * 8 + n;
                float x = acc[m][n];
                if (t == 0) x += btl[o] + btr[o] + bbl[o] + bbr[o];  // bias fold
                h[n] = (_Float16)x;
            }
            *(f16x8*)&Th[((long long)t * TROWS_ + r) * HID_ + o0 + tx * 8] = h;
        }
        return;
    }

    if (bid < GEMM_BLOCKS + TOPK_BLOCKS) {
        // ---------------- Role 1: top-k + local mask ----------------
        const int bi = bid - GEMM_BLOCKS;
        const int b = bi >> 10;
        const int i = bi & 1023;
        for (int j = tid; j < L_; j += 256) {
            int4 q = bbox[b * L_ + j];
            float x1, y1, x2, y2;
            if (am[b * L_ + j] == 0) { x1 = y1 = x2 = y2 = 1e8f; }
            else { x1 = (float)q.x; y1 = (float)q.y; x2 = (float)q.z; y2 = (float)q.w; }
            sm.t.xs[j] = (x1 + x2) * 0.5f;
            sm.t.ys[j] = (y1 + y2) * 0.5f;
            sm.t.mrow[j] = 0.f;
        }
        __syncthreads();
        const float xq = sm.t.xs[i], yq = sm.t.ys[i];
        unsigned long long key[4];
        #pragma unroll
        for (int s = 0; s < 4; ++s) {
            int j = tid + s * 256;
            float dx = xq - sm.t.xs[j], dy = yq - sm.t.ys[j];
            float d = dx * dx + dy * dy;   // exact in fp32 (multiples of 0.25)
            key[s] = ((unsigned long long)__float_as_uint(d) << 32) | (unsigned int)j;
        }
        const int lane = tid & 63, wave = tid >> 6;
        const long long obase = (long long)(b * L_ + i) * K_;
        for (int r = 0; r < K_; ++r) {
            unsigned long long m = key[0] < key[1] ? key[0] : key[1];
            unsigned long long m2 = key[2] < key[3] ? key[2] : key[3];
            if (m2 < m) m = m2;
            #pragma unroll
            for (int off = 1; off < 64; off <<= 1) {
                unsigned long long o = __shfl_xor(m, off, 64);
                if (o < m) m = o;
            }
            if (lane == 0) sm.t.wmin[wave] = m;
            __syncthreads();
            unsigned long long mm = sm.t.wmin[0] < sm.t.wmin[1] ? sm.t.wmin[0] : sm.t.wmin[1];
            unsigned long long mb = sm.t.wmin[2] < sm.t.wmin[3] ? sm.t.wmin[2] : sm.t.wmin[3];
            if (mb < mm) mm = mb;
            if (tid == 0) {
                int w = (int)(mm & 0xffffffffu);
                topk_f[obase + r] = (float)w;
                topk_i[obase + r] = w;
                sm.t.mrow[w] = 1.0f;
            }
            #pragma unroll
            for (int s = 0; s < 4; ++s) if (key[s] == mm) key[s] = ~0ULL;  // remove winner
            __syncthreads();
        }
        f32x4* mrow = (f32x4*)(mask + (long long)(b * L_ + i) * L_);
        const f32x4* src = (const f32x4*)sm.t.mrow;
        __builtin_nontemporal_store(src[tid], mrow + tid);
        return;
    }

    // ---------------- Role 2: layout_emb + LayerNorm ----------------
    {
        const int tok = bid - (GEMM_BLOCKS + TOPK_BLOCKS);
        const int4 q = bbox[tok];
        float v[3];
        #pragma unroll
        for (int s = 0; s < 3; ++s) {
            int e = tid + s * 256;
            int off = e & 127;
            int seg = e >> 7;
            float val;
            if (seg == 0)      val = xt[q.x * 128 + off];
            else if (seg == 1) val = yt[q.y * 128 + off];
            else if (seg == 2) val = xt[q.z * 128 + off];
            else if (seg == 3) val = yt[q.w * 128 + off];
            else if (seg == 4) val = ht[(q.w - q.y) * 128 + off];
            else               val = wt[(q.z - q.x) * 128 + off];
            v[s] = val;
        }
        float mu = block_sum_256(v[0] + v[1] + v[2], sm.l.red) * (1.0f / 768.0f);
        float sq = 0.f;
        #pragma unroll
        for (int s = 0; s < 3; ++s) { float d = v[s] - mu; sq = fmaf(d, d, sq); }
        float var = block_sum_256(sq, sm.l.red) * (1.0f / 768.0f);
        float inv = 1.0f / sqrtf(var + 1e-12f);
        float* orow = lout + (long long)tok * HID_;
        #pragma unroll
        for (int s = 0; s < 3; ++s) {
            int e = tid + s * 256;
            __builtin_nontemporal_store((v[s] - mu) * inv * lng[e] + lnb[e], orow + e);
        }
    }
}

// ---------------------------------------------------------------------------
// p assembly: p[row,:] = T1[r1] + T2[r2] + T3[r3] + T4[r4]  (bias in T1)
// T is fp16 now: read traffic halves (630 MB) and the hot delta band
// (~1.85 MB) is fully L2-resident per XCD. Convert to f32, add, NT-store.
// ---------------------------------------------------------------------------
__device__ __forceinline__ int wrapc(int d) {
    d = d < -1000 ? -1000 : (d > 1000 ? 1000 : d);  // clip [1-MAX2D, MAX2D-1]
    return (d + 1024) & 1023;                        // mod INIT (d >= -1000)
}

__global__ __launch_bounds__(256) void k_passemble(
    const int4* __restrict__ bbox, const int* __restrict__ topk_i,
    const _Float16* __restrict__ Th, float* __restrict__ p)
{
    const int row = blockIdx.x * 4 + (threadIdx.x >> 6);  // (b*L+i)*K + k
    const int lane = threadIdx.x & 63;
    const int b = row / (L_ * K_);
    const int rem = row - b * (L_ * K_);
    const int i = rem / K_;
    const int j = topk_i[row];
    const int4 bi = bbox[b * L_ + i];
    const int4 bj = bbox[b * L_ + j];
    const _Float16* T1 = Th + (long long)wrapc(bi.x - bj.x) * HID_;                       // ex1
    const _Float16* T2 = Th + 1LL * TROWS_ * HID_ + (long long)wrapc(bi.z - bj.z) * HID_; // ex2
    const _Float16* T3 = Th + 2LL * TROWS_ * HID_ + (long long)wrapc(bi.y - bj.y) * HID_; // ey1
    const _Float16* T4 = Th + 3LL * TROWS_ * HID_ + (long long)wrapc(bi.w - bj.w) * HID_; // ey2
    f32x4* prow = (f32x4*)p + (long long)row * 192;
    #pragma unroll
    for (int u = 0; u < 3; ++u) {
        int fv = lane + u * 64;          // f32x4 index in row
        int f = fv * 4;                  // element index
        f16x4 h1 = *(const f16x4*)&T1[f];
        f16x4 h2 = *(const f16x4*)&T2[f];
        f16x4 h3 = *(const f16x4*)&T3[f];
        f16x4 h4 = *(const f16x4*)&T4[f];
        f32x4 o;
        #pragma unroll
        for (int c = 0; c < 4; ++c)
            o[c] = (float)h1[c] + (float)h2[c] + (float)h3[c] + (float)h4[c];
        __builtin_nontemporal_store(o, prow + fv);
    }
}

// ---------------------------------------------------------------------------
extern "C" void kernel_launch(void* const* d_in, const int* in_sizes, int n_in,
                              void* d_out, int out_size, void* d_ws, size_t ws_size,
                              hipStream_t stream)
{
    const int4* bbox = (const int4*)d_in[0];
    const int* am    = (const int*)d_in[1];
    const float* xt  = (const float*)d_in[2];
    const float* yt  = (const float*)d_in[3];
    const float* ht  = (const float*)d_in[4];
    const float* wt  = (const float*)d_in[5];
    const float* Wtl = (const float*)d_in[6];
    const float* btl = (const float*)d_in[7];
    const float* Wtr = (const float*)d_in[8];
    const float* btr = (const float*)d_in[9];
    const float* Wbl = (const float*)d_in[10];
    const float* bbl = (const float*)d_in[11];
    const float* Wbr = (const float*)d_in[12];
    const float* bbr = (const float*)d_in[13];
    const float* lng = (const float*)d_in[14];
    const float* lnb = (const float*)d_in[15];
    // d_in[16] = params (50) — baked into K_

    float* out = (float*)d_out;
    float* ws = (float*)d_ws;
    float* ST = ws + WS_ST;
    float* UT = ws + WS_UT;
    _Float16* Th = (_Float16*)(ws + WS_T);
    int* topk_i = (int*)(ws + WS_TI);

    k_pre<<<dim3(PE_ + 288), dim3(256), 0, stream>>>(Wtl, Wtr, Wbl, Wbr, ST, UT);
    k_mega<<<dim3(GEMM_BLOCKS + TOPK_BLOCKS + LN_BLOCKS), dim3(256), 0, stream>>>(
        ST, UT, btl, btr, bbl, bbr, Th,
        bbox, am, out + OUT2, topk_i, out + OUT3,
        xt, yt, ht, wt, lng, lnb, out + OUT0);
    k_passemble<<<dim3(B_ * L_ * K_ / 4), dim3(256), 0, stream>>>(
        bbox, topk_i, Th, out + OUT1);
}